// Round 16
// baseline (3352.721 us; speedup 1.0000x reference)
//
#include <hip/hip_runtime.h>

#define S_LEN 256
#define B_SZ 64
#define I_SZ 512
#define H_SZ 1024
#define NBLK 256

typedef __bf16 bf16x8 __attribute__((ext_vector_type(8)));
typedef float f32x4 __attribute__((ext_vector_type(4)));
typedef unsigned long long u64;

__device__ __forceinline__ float sigmoidf_(float x){ return 1.f/(1.f + expf(-x)); }

// ---- device-coherent (MALL) access helpers: bypass L1+L2, no fences ----
__device__ __forceinline__ u64 ld_cc64(const u64* p){
  return __hip_atomic_load(p, __ATOMIC_RELAXED, __HIP_MEMORY_SCOPE_AGENT);
}
__device__ __forceinline__ void st_cc16(__bf16* p, __bf16 v){
  unsigned short b = __builtin_bit_cast(unsigned short, v);
  __hip_atomic_store((unsigned short*)p, b, __ATOMIC_RELAXED, __HIP_MEMORY_SCOPE_AGENT);
}
__device__ __forceinline__ void st_cc32(float* p, float v){
  __hip_atomic_store(p, v, __ATOMIC_RELAXED, __HIP_MEMORY_SCOPE_AGENT);
}
__device__ __forceinline__ float ld_cc32f(const float* p){
  return __hip_atomic_load(p, __ATOMIC_RELAXED, __HIP_MEMORY_SCOPE_AGENT);
}

// ---------------- prep kernels ----------------

__global__ __launch_bounds__(64) void pack_w4_k(const float* __restrict__ Wf, const float* __restrict__ Wi,
                                                const float* __restrict__ Wu, const float* __restrict__ Wo,
                                                __bf16* __restrict__ W4p){
  int blk = blockIdx.x;           // nt16*48 + kb
  int nt = blk / 48, kb = blk % 48;
  int l = threadIdx.x;
  int n = nt*16 + (l & 15);
  int g = n >> 10, h = n & 1023;
  const float* W = (g==0)?Wf:((g==1)?Wi:((g==2)?Wu:Wo));
  int k0 = kb*32 + ((l>>4)<<3);
  __bf16 tmp[8];
#pragma unroll
  for (int j=0;j<8;j++) tmp[j] = (__bf16)W[(size_t)(k0+j)*H_SZ + h];
  *reinterpret_cast<bf16x8*>(W4p + ((size_t)blk*64 + l)*8) = *reinterpret_cast<bf16x8*>(tmp);
}

__global__ __launch_bounds__(64) void pack_wc_k(const float* __restrict__ Wc, __bf16* __restrict__ Wcp){
  int blk = blockIdx.x;           // nt16*32 + kb
  int nt = blk / 32, kb = blk % 32;
  int l = threadIdx.x;
  int n = nt*16 + (l & 15);
  int k0 = kb*32 + ((l>>4)<<3);
  __bf16 tmp[8];
#pragma unroll
  for (int j=0;j<8;j++) tmp[j] = (__bf16)Wc[(size_t)(k0+j)*H_SZ + n];
  *reinterpret_cast<bf16x8*>(Wcp + ((size_t)blk*64 + l)*8) = *reinterpret_cast<bf16x8*>(tmp);
}

// x packed into fragment order: xF[(s*4+mt)][kb 0..15][lane 0..63] 16B granules
__global__ __launch_bounds__(256) void pack_x_k(const float* __restrict__ x, __bf16* __restrict__ xF){
  int bid = blockIdx.x;           // s*4 + mt
  int s = bid >> 2, mt = bid & 3;
#pragma unroll
  for (int j=0;j<4;j++){
    int G = j*256 + threadIdx.x;  // granule 0..1023
    int kb = G >> 6, lane = G & 63;
    int b = mt*16 + (lane & 15);
    int k0 = kb*32 + ((lane>>4)<<3);
    const float* src = x + ((size_t)s*B_SZ + b)*I_SZ + k0;
    float4 v0 = *reinterpret_cast<const float4*>(src);
    float4 v1 = *reinterpret_cast<const float4*>(src+4);
    __bf16 t[8] = {(__bf16)v0.x,(__bf16)v0.y,(__bf16)v0.z,(__bf16)v0.w,
                   (__bf16)v1.x,(__bf16)v1.y,(__bf16)v1.z,(__bf16)v1.w};
    *reinterpret_cast<bf16x8*>(xF + ((size_t)bid*1024 + G)*8) = *reinterpret_cast<bf16x8*>(t);
  }
}

__global__ void init_h_k(__bf16* __restrict__ hxF){
  int i = blockIdx.x*blockDim.x + threadIdx.x;   // 65536 threads
  hxF[i] = (__bf16)0.f;
}

// ---------------- global split arrive/wait flag barrier (deterministic base) ----------------
// Deterministic across r6/r7/r8/r14/r15 (absmax bit-identical). Group-local
// variants showed racy drift (r5/r11/r12) -> retired. This round adds a
// half-split epoch (3 epochs/step) but keeps the 256-flag global fan-in.
__device__ __forceinline__ void bar_arrive(unsigned* flags, unsigned target){
  asm volatile("" ::: "memory");
  __syncthreads();   // per-wave vmcnt(0): all coherent stores drained (acked) first
  if (threadIdx.x == 0)
    __hip_atomic_store(&flags[blockIdx.x], target, __ATOMIC_RELAXED, __HIP_MEMORY_SCOPE_AGENT);
}
__device__ __forceinline__ void bar_wait(const unsigned* flags, unsigned target){
  if (threadIdx.x < 64){
    const u64* f = (const u64*)flags;
    int i0 = (int)threadIdx.x * 2;
    for(;;){
      u64 a = __hip_atomic_load(f+i0,   __ATOMIC_RELAXED, __HIP_MEMORY_SCOPE_AGENT);
      u64 b = __hip_atomic_load(f+i0+1, __ATOMIC_RELAXED, __HIP_MEMORY_SCOPE_AGENT);
      bool ok = ((unsigned)a >= target) && ((unsigned)(a>>32) >= target)
             && ((unsigned)b >= target) && ((unsigned)(b>>32) >= target);
      if (__all(ok)) break;
      __builtin_amdgcn_s_sleep(1);
    }
  }
  __syncthreads();
}

// ---------------- persistent kernel: all 256 steps ----------------
// 3 epochs per step (flags monotone, target = 3s+k):
//   3s+1 : act half-A (h<512) drained. Half-A blocks ((nt64&15)<8) signal via
//          their 3s+2 arrive; half-B blocks signal 3s+1 EARLY (their flag
//          gates nothing at epoch A -- hxF overwrite is gated by 3s+2).
//   3s+2 : ALL act drained (full p1 arrive).
//   3s+3 : p2 done (hxF written).
// p2 overlaps: after wait(3s+1) it loads+MFMAs act kb 0..15 while half-B
// producers finish storing; wait(3s+2) is then nearly free.
// Exchange buffers in MFMA-fragment order in global memory:
//   hxF[mt 0..3][kb 0..31][lane 0..63]{8 bf16}
//   actF[g 0..3][oct 0..7][kb 0..31][slot 0..31]{8 bf16}, slot = kq*8+r8

__global__ __launch_bounds__(256, 1) void qlstm_persist_k(
    const __bf16* __restrict__ xF,
    __bf16* hxF,
    const __bf16* __restrict__ W4p, const __bf16* __restrict__ Wcp,
    const float* __restrict__ bfv, const float* __restrict__ biv,
    const float* __restrict__ buv, const float* __restrict__ bov,
    const float* __restrict__ pf, const float* __restrict__ piq,
    const float* __restrict__ pu, const float* __restrict__ po,
    const float* __restrict__ WcLast, const float* __restrict__ bc,
    __bf16* actF, float* zact,
    float* __restrict__ out,
    unsigned* flags)
{
  __shared__ __align__(16) __bf16 ldsWc[2*32*64*8];   // 64 KiB, persistent
  __shared__ __align__(16) char ldsA[32768];          // 32 KiB: p1 hx stage only
  __shared__ float gx[4][8][32];
  __shared__ float pre4[16][4];

  const int tid = threadIdx.x;
  const int bid = blockIdx.x;
  const int wave = tid >> 6;
  const int l = tid & 63;
  const int col = l & 15;
  const int kq = l >> 4;

  // ---- phase-1 ids ----
  const int mt1 = bid >> 6;
  const int nt64 = bid & 63;
  const int nt16 = nt64*4 + wave;
  const int g1 = nt16 >> 6;
  const int h1 = (nt16*16 + col) & 1023;
  const bool isHalfA = ((nt64 & 15) < 8);  // all 16 cols of this block in h<512

  // ---- phase-2 ids ----
  const int mt2 = bid >> 5;                // 0..7 -> 8-row batch tile
  const int ht  = bid & 31;                // 32 h-cols
  const int r2 = tid >> 5;
  const int c2 = tid & 31;
  const int b2 = mt2*8 + r2;
  const int h2 = ht*32 + c2;
  const int slot2 = kq*8 + (l & 7);        // A-frag slot (lanes l, l+8 share)

  // ---- W4 fragments -> registers/AGPRs ----
  bf16x8 wfrag[48];
  {
    const bf16x8* src = (const bf16x8*)(W4p + ((size_t)nt16*48*64 + (size_t)l)*8);
#pragma unroll
    for (int kb=0;kb<48;kb++) wfrag[kb] = src[(size_t)kb*64];
  }
  // ---- Wc frags (nt16 = ht*2, ht*2+1) -> LDS, persistent ----
  {
    const u64* src = (const u64*)(Wcp + (size_t)(ht*2)*32*64*8);
    u64* dst = (u64*)ldsWc;
    for (int i = tid; i < 8192; i += 256) dst[i] = src[i];
  }

  const float* bptr = (g1==0)?bfv:((g1==1)?biv:((g1==2)?buv:bov));
  const float bias1 = bptr[h1];
  const bool isU1 = (g1==2);
  const bool isQb = ((nt64 & 15) == 0);
  const int gq = nt64 >> 4;
  float pq0=0.f,pq1=0.f,pq2=0.f,pq3=0.f;
  if (isQb && wave==0){
    const float* pq = (gq==0)?pf:((gq==1)?piq:((gq==2)?pu:po));
    pq0=pq[0]; pq1=pq[1]; pq2=pq[2]; pq3=pq[3];
  }

  const float wl2 = WcLast[h2];
  const float bc2 = bc[h2];
  float creg = 0.f;

  // loop-invariant store indices
  // actF elem = (((g*8+oct)*32 + kb)*32 + slot)*8 + e
  size_t eis[4];
#pragma unroll
  for (int rr=0;rr<4;rr++){
    int brow = mt1*16 + (kq<<2) + rr;
    eis[rr] = (((size_t)(g1*8 + (brow>>3))*32 + (h1>>5))*32
               + (size_t)((((h1>>3)&3)<<3) + (brow&7)))*8 + (h1&7);
  }
  // phase-2 hx store: hxF elem = ((grp*32 + kb)*64 + lane)*8 + e
  const int laneh = (b2 & 15) + (((c2 >> 3) & 3) << 4);
  const size_t hei = ((size_t)((b2>>4)*32 + ht)*64 + laneh)*8 + (c2 & 7);

  __syncthreads();   // Wc staged

  const size_t SBH = (size_t)S_LEN*B_SZ*H_SZ;

  for (int s = 0; s < S_LEN; ++s){
    const unsigned T = 3u*(unsigned)s;
    // ================= phase 1: pre + activations + qgate =================
    {
      f32x4 acc[4] = {{0,0,0,0},{0,0,0,0},{0,0,0,0},{0,0,0,0}};
      // x-part (read-only, L2): loads + MFMAs BEFORE barrier wait
      const bf16x8* xp = (const bf16x8*)xF + (size_t)(s*4 + mt1)*1024 + l;
      {
        bf16x8 xf[8];
#pragma unroll
        for (int j=0;j<8;j++) xf[j] = xp[(size_t)j*64];
#pragma unroll
        for (int j=0;j<8;j++)
          acc[j&3] = __builtin_amdgcn_mfma_f32_16x16x32_bf16(xf[j], wfrag[j], acc[j&3], 0,0,0);
#pragma unroll
        for (int j=0;j<8;j++) xf[j] = xp[(size_t)(8+j)*64];
#pragma unroll
        for (int j=0;j<8;j++)
          acc[j&3] = __builtin_amdgcn_mfma_f32_16x16x32_bf16(xf[j], wfrag[8+j], acc[j&3], 0,0,0);
      }

      bar_wait(flags, T);                  // p2(s-1) done: hx(s) visible

      // stage hx (identity memcpy: coalesced loads -> contiguous ds_write)
      {
        const u64* hp = (const u64*)hxF + (size_t)mt1*4096;
        u64 slo[8], shi[8];
#pragma unroll
        for (int i=0;i<8;i++){
          int G = tid + 256*i;
          slo[i] = ld_cc64(hp + (size_t)G*2);
          shi[i] = ld_cc64(hp + (size_t)G*2 + 1);
        }
#pragma unroll
        for (int i=0;i<8;i++){
          int G = tid + 256*i;
          ulonglong2 v; v.x = slo[i]; v.y = shi[i];
          *reinterpret_cast<ulonglong2*>(ldsA + (size_t)G*16) = v;
        }
      }
      __syncthreads();                     // hx reads complete (vmcnt drained)

      // half-B blocks: signal epoch A early -- their flag gates nothing at A
      if (!isHalfA && tid == 0)
        __hip_atomic_store(&flags[bid], T+1u, __ATOMIC_RELAXED, __HIP_MEMORY_SCOPE_AGENT);

#pragma unroll
      for (int kb=0;kb<32;kb++){
        bf16x8 a = *reinterpret_cast<const bf16x8*>(ldsA + ((size_t)kb*64 + l)*16);
        acc[kb&3] = __builtin_amdgcn_mfma_f32_16x16x32_bf16(a, wfrag[16+kb], acc[kb&3], 0,0,0);
      }
      f32x4 r = (acc[0]+acc[1])+(acc[2]+acc[3]);
      float pr[4];
#pragma unroll
      for (int rr=0;rr<4;rr++){
        float p = r[rr] + bias1;
        pr[rr] = p;
        float a = isU1 ? tanhf(p) : sigmoidf_(p);
        st_cc16(&actF[eis[rr]], (__bf16)a);
      }
      if (isQb && wave==0){
        if (col < 4){
#pragma unroll
          for (int rr=0;rr<4;rr++) pre4[(kq<<2)+rr][col] = pr[rr];
        }
        if (l < 16){
          float th = pre4[l][0]*pq0 + pre4[l][1]*pq1 + pre4[l][2]*pq2 + pre4[l][3]*pq3;
          float z = cosf(2.f*th);
          st_cc32(&zact[gq*B_SZ + mt1*16 + l], (gq==2) ? z : sigmoidf_(z));
        }
      }
    }

    bar_arrive(flags, T+2u);               // all act (this block) drained
    bar_wait(flags, T+1u);                 // act half-A visible everywhere

    // ================= phase 2: comb + cell update =================
    {
      // zact loads first (writers are half-A blocks -> visible at epoch A)
      float zf = ld_cc32f(&zact[      b2]);
      float zi = ld_cc32f(&zact[ 64 + b2]);
      float zu = ld_cc32f(&zact[128 + b2]);
      float zo = ld_cc32f(&zact[192 + b2]);

      // act fragments DIRECT to registers: 4 chunks of 8 kb, double-buffered.
      // Chunks 0,1 (kb 0..15, h<512) after epoch A; chunks 2,3 after epoch B.
      const u64* ap = (const u64*)actF + (size_t)(wave*8 + mt2)*2048 + (size_t)slot2*2;
      const bf16x8* bf0 = (const bf16x8*)ldsWc + l;
      const bf16x8* bf1 = bf0 + 2048;
      f32x4 acc2[4] = {{0,0,0,0},{0,0,0,0},{0,0,0,0},{0,0,0,0}};
      u64 A0lo[8], A0hi[8], A1lo[8], A1hi[8];
#pragma unroll
      for (int i=0;i<8;i++){
        A0lo[i] = ld_cc64(ap + (size_t)i*64);
        A0hi[i] = ld_cc64(ap + (size_t)i*64 + 1);
      }
      // chunk 0 in flight; issue chunk 1, consume chunk 0
#pragma unroll
      for (int i=0;i<8;i++){
        A1lo[i] = ld_cc64(ap + (size_t)(8+i)*64);
        A1hi[i] = ld_cc64(ap + (size_t)(8+i)*64 + 1);
      }
#pragma unroll
      for (int i=0;i<8;i++){
        union{u64 u[2]; bf16x8 v;} a; a.u[0]=A0lo[i]; a.u[1]=A0hi[i];
        acc2[i&1]     = __builtin_amdgcn_mfma_f32_16x16x32_bf16(a.v, bf0[(size_t)i*64], acc2[i&1], 0,0,0);
        acc2[2+(i&1)] = __builtin_amdgcn_mfma_f32_16x16x32_bf16(a.v, bf1[(size_t)i*64], acc2[2+(i&1)], 0,0,0);
      }

      bar_wait(flags, T+2u);               // all act visible (nearly free here)

#pragma unroll
      for (int i=0;i<8;i++){
        A0lo[i] = ld_cc64(ap + (size_t)(16+i)*64);
        A0hi[i] = ld_cc64(ap + (size_t)(16+i)*64 + 1);
      }
#pragma unroll
      for (int i=0;i<8;i++){
        int kb = 8+i;
        union{u64 u[2]; bf16x8 v;} a; a.u[0]=A1lo[i]; a.u[1]=A1hi[i];
        acc2[kb&1]     = __builtin_amdgcn_mfma_f32_16x16x32_bf16(a.v, bf0[(size_t)kb*64], acc2[kb&1], 0,0,0);
        acc2[2+(kb&1)] = __builtin_amdgcn_mfma_f32_16x16x32_bf16(a.v, bf1[(size_t)kb*64], acc2[2+(kb&1)], 0,0,0);
      }
#pragma unroll
      for (int i=0;i<8;i++){
        A1lo[i] = ld_cc64(ap + (size_t)(24+i)*64);
        A1hi[i] = ld_cc64(ap + (size_t)(24+i)*64 + 1);
      }
#pragma unroll
      for (int i=0;i<8;i++){
        int kb = 16+i;
        union{u64 u[2]; bf16x8 v;} a; a.u[0]=A0lo[i]; a.u[1]=A0hi[i];
        acc2[kb&1]     = __builtin_amdgcn_mfma_f32_16x16x32_bf16(a.v, bf0[(size_t)kb*64], acc2[kb&1], 0,0,0);
        acc2[2+(kb&1)] = __builtin_amdgcn_mfma_f32_16x16x32_bf16(a.v, bf1[(size_t)kb*64], acc2[2+(kb&1)], 0,0,0);
      }
#pragma unroll
      for (int i=0;i<8;i++){
        int kb = 24+i;
        union{u64 u[2]; bf16x8 v;} a; a.u[0]=A1lo[i]; a.u[1]=A1hi[i];
        acc2[kb&1]     = __builtin_amdgcn_mfma_f32_16x16x32_bf16(a.v, bf0[(size_t)kb*64], acc2[kb&1], 0,0,0);
        acc2[2+(kb&1)] = __builtin_amdgcn_mfma_f32_16x16x32_bf16(a.v, bf1[(size_t)kb*64], acc2[2+(kb&1)], 0,0,0);
      }

      f32x4 rA = acc2[0]+acc2[1];
      f32x4 rB = acc2[2]+acc2[3];
#pragma unroll
      for (int rr=0;rr<4;rr++){
        int row = (kq<<2) + rr;            // rows 8..15 duplicates, discard
        if (row < 8){
          gx[wave][row][col]      = rA[rr];
          gx[wave][row][16 + col] = rB[rr];
        }
      }
      __syncthreads();

      float fg = sigmoidf_(gx[0][r2][c2] + bc2 + zf*wl2);
      float ig = sigmoidf_(gx[1][r2][c2] + bc2 + zi*wl2);
      float gg = tanhf(    gx[2][r2][c2] + bc2 + zu*wl2);
      float og = sigmoidf_(gx[3][r2][c2] + bc2 + zo*wl2);
      float cn = fg*creg + ig*gg;
      creg = cn;
      float hn = og*tanhf(cn);
      st_cc16(&hxF[hei], (__bf16)hn);
      size_t idx = (size_t)b2*H_SZ + h2;
      __builtin_nontemporal_store(hn, &out[(size_t)s*B_SZ*H_SZ + idx]);
      if (s == S_LEN-1){
        __builtin_nontemporal_store(hn, &out[SBH + idx]);
        __builtin_nontemporal_store(cn, &out[SBH + (size_t)B_SZ*H_SZ + idx]);
      }
    }

    bar_arrive(flags, T+3u);               // hx(s+1 input) drained
  }
}

// ---------------- launch ----------------

extern "C" void kernel_launch(void* const* d_in, const int* in_sizes, int n_in,
                              void* d_out, int out_size, void* d_ws, size_t ws_size,
                              hipStream_t stream){
  const float* inputs = (const float*)d_in[0];
  const float* Wf  = (const float*)d_in[1];
  const float* bf_ = (const float*)d_in[2];
  const float* Wi  = (const float*)d_in[3];
  const float* bi_ = (const float*)d_in[4];
  const float* Wu  = (const float*)d_in[5];
  const float* bu_ = (const float*)d_in[6];
  const float* Wo  = (const float*)d_in[7];
  const float* bo_ = (const float*)d_in[8];
  const float* pf  = (const float*)d_in[9];
  const float* piq = (const float*)d_in[10];
  const float* pu  = (const float*)d_in[11];
  const float* po  = (const float*)d_in[12];
  const float* Wc  = (const float*)d_in[13];
  const float* bc  = (const float*)d_in[14];
  float* out = (float*)d_out;

  __bf16* W4p = (__bf16*)d_ws;                        // 6,291,456 bf16
  __bf16* Wcp = W4p + (size_t)256*48*64*8;            // 1,048,576 bf16
  __bf16* xF  = Wcp + (size_t)64*32*64*8;             // 8,388,608 bf16
  __bf16* actF = xF + (size_t)S_LEN*B_SZ*I_SZ;        // 262,144 bf16
  __bf16* hxF = actF + (size_t)4*B_SZ*H_SZ;           // 65,536 bf16
  float*  zact = (float*)(hxF + (size_t)B_SZ*H_SZ);   // 256 f32
  unsigned* flags = (unsigned*)(zact + 256);          // 256 u32

  pack_w4_k<<<256*48, 64, 0, stream>>>(Wf, Wi, Wu, Wo, W4p);
  pack_wc_k<<<64*32, 64, 0, stream>>>(Wc, Wcp);
  pack_x_k<<<S_LEN*4, 256, 0, stream>>>(inputs, xF);
  init_h_k<<<256, 256, 0, stream>>>(hxF);
  hipMemsetAsync(flags, 0, NBLK*sizeof(unsigned), stream);

  qlstm_persist_k<<<NBLK, 256, 0, stream>>>(
      xF, hxF, W4p, Wcp, bf_, bi_, bu_, bo_, pf, piq, pu, po,
      Wc + (size_t)H_SZ*H_SZ, bc, actF, zact, out, flags);
}

// Round 17
// 3230.476 us; speedup vs baseline: 1.0378x; 1.0378x over previous
//
#include <hip/hip_runtime.h>

#define S_LEN 256
#define B_SZ 64
#define I_SZ 512
#define H_SZ 1024
#define NBLK 256

typedef __bf16 bf16x8 __attribute__((ext_vector_type(8)));
typedef float f32x4 __attribute__((ext_vector_type(4)));
typedef unsigned long long u64;

__device__ __forceinline__ float sigmoidf_(float x){ return 1.f/(1.f + expf(-x)); }

// ---- device-coherent (MALL) access helpers: bypass L1+L2, no fences ----
__device__ __forceinline__ u64 ld_cc64(const u64* p){
  return __hip_atomic_load(p, __ATOMIC_RELAXED, __HIP_MEMORY_SCOPE_AGENT);
}
__device__ __forceinline__ void st_cc64(u64* p, u64 v){
  __hip_atomic_store(p, v, __ATOMIC_RELAXED, __HIP_MEMORY_SCOPE_AGENT);
}
__device__ __forceinline__ void st_cc32(float* p, float v){
  __hip_atomic_store(p, v, __ATOMIC_RELAXED, __HIP_MEMORY_SCOPE_AGENT);
}
__device__ __forceinline__ float ld_cc32f(const float* p){
  return __hip_atomic_load(p, __ATOMIC_RELAXED, __HIP_MEMORY_SCOPE_AGENT);
}

// ---------------- prep kernels ----------------

__global__ __launch_bounds__(64) void pack_w4_k(const float* __restrict__ Wf, const float* __restrict__ Wi,
                                                const float* __restrict__ Wu, const float* __restrict__ Wo,
                                                __bf16* __restrict__ W4p){
  int blk = blockIdx.x;           // nt16*48 + kb
  int nt = blk / 48, kb = blk % 48;
  int l = threadIdx.x;
  int n = nt*16 + (l & 15);
  int g = n >> 10, h = n & 1023;
  const float* W = (g==0)?Wf:((g==1)?Wi:((g==2)?Wu:Wo));
  int k0 = kb*32 + ((l>>4)<<3);
  __bf16 tmp[8];
#pragma unroll
  for (int j=0;j<8;j++) tmp[j] = (__bf16)W[(size_t)(k0+j)*H_SZ + h];
  *reinterpret_cast<bf16x8*>(W4p + ((size_t)blk*64 + l)*8) = *reinterpret_cast<bf16x8*>(tmp);
}

__global__ __launch_bounds__(64) void pack_wc_k(const float* __restrict__ Wc, __bf16* __restrict__ Wcp){
  int blk = blockIdx.x;           // nt16*32 + kb
  int nt = blk / 32, kb = blk % 32;
  int l = threadIdx.x;
  int n = nt*16 + (l & 15);
  int k0 = kb*32 + ((l>>4)<<3);
  __bf16 tmp[8];
#pragma unroll
  for (int j=0;j<8;j++) tmp[j] = (__bf16)Wc[(size_t)(k0+j)*H_SZ + n];
  *reinterpret_cast<bf16x8*>(Wcp + ((size_t)blk*64 + l)*8) = *reinterpret_cast<bf16x8*>(tmp);
}

// x packed into fragment order: xF[(s*4+mt)][kb 0..15][lane 0..63] 16B granules
__global__ __launch_bounds__(256) void pack_x_k(const float* __restrict__ x, __bf16* __restrict__ xF){
  int bid = blockIdx.x;           // s*4 + mt
  int s = bid >> 2, mt = bid & 3;
#pragma unroll
  for (int j=0;j<4;j++){
    int G = j*256 + threadIdx.x;  // granule 0..1023
    int kb = G >> 6, lane = G & 63;
    int b = mt*16 + (lane & 15);
    int k0 = kb*32 + ((lane>>4)<<3);
    const float* src = x + ((size_t)s*B_SZ + b)*I_SZ + k0;
    float4 v0 = *reinterpret_cast<const float4*>(src);
    float4 v1 = *reinterpret_cast<const float4*>(src+4);
    __bf16 t[8] = {(__bf16)v0.x,(__bf16)v0.y,(__bf16)v0.z,(__bf16)v0.w,
                   (__bf16)v1.x,(__bf16)v1.y,(__bf16)v1.z,(__bf16)v1.w};
    *reinterpret_cast<bf16x8*>(xF + ((size_t)bid*1024 + G)*8) = *reinterpret_cast<bf16x8*>(t);
  }
}

__global__ void init_h_k(__bf16* __restrict__ hxF){
  int i = blockIdx.x*blockDim.x + threadIdx.x;   // 65536 threads
  hxF[i] = (__bf16)0.f;
}

// ---------------- global split arrive/wait flag barrier (deterministic base) ----------------
// Deterministic across r6/r7/r8/r14/r15/r16 (absmax bit-identical). Group-local
// variants showed racy drift (r5/r11/r12) -> retired.
__device__ __forceinline__ void bar_arrive(unsigned* flags, unsigned target){
  asm volatile("" ::: "memory");
  __syncthreads();   // per-wave vmcnt(0): all coherent stores drained first
  if (threadIdx.x == 0)
    __hip_atomic_store(&flags[blockIdx.x], target, __ATOMIC_RELAXED, __HIP_MEMORY_SCOPE_AGENT);
}
__device__ __forceinline__ void bar_wait(const unsigned* flags, unsigned target){
  if (threadIdx.x < 64){
    const u64* f = (const u64*)flags;
    int i0 = (int)threadIdx.x * 2;
    for(;;){
      u64 a = __hip_atomic_load(f+i0,   __ATOMIC_RELAXED, __HIP_MEMORY_SCOPE_AGENT);
      u64 b = __hip_atomic_load(f+i0+1, __ATOMIC_RELAXED, __HIP_MEMORY_SCOPE_AGENT);
      bool ok = ((unsigned)a >= target) && ((unsigned)(a>>32) >= target)
             && ((unsigned)b >= target) && ((unsigned)(b>>32) >= target);
      if (__all(ok)) break;
      __builtin_amdgcn_s_sleep(1);
    }
  }
  __syncthreads();
}

// ---------------- persistent kernel: all 256 steps ----------------
// r15 base (2 epochs/step, global barrier, p2 direct-reg act loads) +
// WIDE exchange stores: act and hx stores go through a wave-local LDS
// transpose so each granule (16B) is written by ONE lane as 2x8B coherent
// stores in 128B-contiguous runs (was 1024/256 scattered 2B stores per
// block -> partial-sector RMW inflating FETCH/WRITE and store-drain time).
// out stores moved AFTER the arrive (never read in-kernel; drain overlaps
// the next step's poll).
// Exchange buffers in MFMA-fragment order in global memory:
//   hxF[mt 0..3][kb 0..31][lane 0..63]{8 bf16}
//   actF[g 0..3][oct 0..7][kb 0..31][slot 0..31]{8 bf16}, slot = kq*8+r8

__global__ __launch_bounds__(256, 1) void qlstm_persist_k(
    const __bf16* __restrict__ xF,
    __bf16* hxF,
    const __bf16* __restrict__ W4p, const __bf16* __restrict__ Wcp,
    const float* __restrict__ bfv, const float* __restrict__ biv,
    const float* __restrict__ buv, const float* __restrict__ bov,
    const float* __restrict__ pf, const float* __restrict__ piq,
    const float* __restrict__ pu, const float* __restrict__ po,
    const float* __restrict__ WcLast, const float* __restrict__ bc,
    __bf16* actF, float* zact,
    float* __restrict__ out,
    unsigned* flags)
{
  __shared__ __align__(16) __bf16 ldsWc[2*32*64*8];   // 64 KiB, persistent
  __shared__ __align__(16) char ldsA[32768];          // 32 KiB: p1 hx stage
  __shared__ __align__(16) __bf16 acts[4][16][16];    // 2 KiB: p1 act transpose
  __shared__ __align__(16) __bf16 hxs[8][32];         // 512 B: p2 hx transpose
  __shared__ float gx[4][8][32];
  __shared__ float pre4[16][4];

  const int tid = threadIdx.x;
  const int bid = blockIdx.x;
  const int wave = tid >> 6;
  const int l = tid & 63;
  const int col = l & 15;
  const int kq = l >> 4;

  // ---- phase-1 ids ----
  const int mt1 = bid >> 6;
  const int nt64 = bid & 63;
  const int nt16 = nt64*4 + wave;
  const int g1 = nt16 >> 6;
  const int h1 = (nt16*16 + col) & 1023;

  // ---- phase-2 ids ----
  const int mt2 = bid >> 5;                // 0..7 -> 8-row batch tile
  const int ht  = bid & 31;                // 32 h-cols
  const int r2 = tid >> 5;
  const int c2 = tid & 31;
  const int b2 = mt2*8 + r2;
  const int h2 = ht*32 + c2;
  const int slot2 = kq*8 + (l & 7);        // A-frag slot (lanes l, l+8 share)

  // ---- W4 fragments -> registers/AGPRs ----
  bf16x8 wfrag[48];
  {
    const bf16x8* src = (const bf16x8*)(W4p + ((size_t)nt16*48*64 + (size_t)l)*8);
#pragma unroll
    for (int kb=0;kb<48;kb++) wfrag[kb] = src[(size_t)kb*64];
  }
  // ---- Wc frags (nt16 = ht*2, ht*2+1) -> LDS, persistent ----
  {
    const u64* src = (const u64*)(Wcp + (size_t)(ht*2)*32*64*8);
    u64* dst = (u64*)ldsWc;
    for (int i = tid; i < 8192; i += 256) dst[i] = src[i];
  }

  const float* bptr = (g1==0)?bfv:((g1==1)?biv:((g1==2)?buv:bov));
  const float bias1 = bptr[h1];
  const bool isU1 = (g1==2);
  const bool isQb = ((nt64 & 15) == 0);
  const int gq = nt64 >> 4;
  float pq0=0.f,pq1=0.f,pq2=0.f,pq3=0.f;
  if (isQb && wave==0){
    const float* pq = (gq==0)?pf:((gq==1)?piq:((gq==2)?pu:po));
    pq0=pq[0]; pq1=pq[1]; pq2=pq[2]; pq3=pq[3];
  }

  const float wl2 = WcLast[h2];
  const float bc2 = bc[h2];
  float creg = 0.f;

  // ---- loop-invariant WIDE-store addresses ----
  // p1 act: lane j<32 stores granule (row = j&15, half = j>>4) of its wave tile
  u64* actw = nullptr;
  {
    if (l < 32){
      int row = l & 15, half = l >> 4;
      int brow = mt1*16 + row;
      int oct = brow >> 3, r8b = brow & 7;
      int h0 = nt16*16 + half*8;
      int kbA = (h0 >> 5) & 31;
      int kq8A = (h0 >> 3) & 3;
      int slotA = kq8A*8 + r8b;
      size_t eb = (((size_t)(g1*8 + oct)*32 + kbA)*32 + slotA)*8;  // elem idx
      actw = (u64*)actF + eb/4;
    }
  }
  // p2 hx: lane j<8 of each wave stores granule (local row = 2*wave + (j>>2), cg = j&3)
  u64* hxw = nullptr;
  {
    if (l < 8){
      int lr = 2*wave + (l >> 2);
      int cg = l & 3;
      int b = mt2*8 + lr;
      int laneg = (b & 15) + 16*cg;
      size_t eb = (((size_t)(b >> 4)*32 + ht)*64 + laneg)*8;       // elem idx
      hxw = (u64*)hxF + eb/4;
    }
  }

  __syncthreads();   // Wc staged

  const size_t SBH = (size_t)S_LEN*B_SZ*H_SZ;

  for (int s = 0; s < S_LEN; ++s){
    // ================= phase 1: pre + activations + qgate =================
    {
      f32x4 acc[4] = {{0,0,0,0},{0,0,0,0},{0,0,0,0},{0,0,0,0}};
      // x-part (read-only, L2): loads + MFMAs BEFORE barrier wait
      const bf16x8* xp = (const bf16x8*)xF + (size_t)(s*4 + mt1)*1024 + l;
      {
        bf16x8 xf[8];
#pragma unroll
        for (int j=0;j<8;j++) xf[j] = xp[(size_t)j*64];
#pragma unroll
        for (int j=0;j<8;j++)
          acc[j&3] = __builtin_amdgcn_mfma_f32_16x16x32_bf16(xf[j], wfrag[j], acc[j&3], 0,0,0);
#pragma unroll
        for (int j=0;j<8;j++) xf[j] = xp[(size_t)(8+j)*64];
#pragma unroll
        for (int j=0;j<8;j++)
          acc[j&3] = __builtin_amdgcn_mfma_f32_16x16x32_bf16(xf[j], wfrag[8+j], acc[j&3], 0,0,0);
      }

      bar_wait(flags, (unsigned)(2*s));    // p2(s-1) done: hx(s) visible

      // stage hx (identity memcpy: coalesced loads -> contiguous ds_write)
      {
        const u64* hp = (const u64*)hxF + (size_t)mt1*4096;
        u64 slo[8], shi[8];
#pragma unroll
        for (int i=0;i<8;i++){
          int G = tid + 256*i;
          slo[i] = ld_cc64(hp + (size_t)G*2);
          shi[i] = ld_cc64(hp + (size_t)G*2 + 1);
        }
#pragma unroll
        for (int i=0;i<8;i++){
          int G = tid + 256*i;
          ulonglong2 v; v.x = slo[i]; v.y = shi[i];
          *reinterpret_cast<ulonglong2*>(ldsA + (size_t)G*16) = v;
        }
      }
      __syncthreads();

#pragma unroll
      for (int kb=0;kb<32;kb++){
        bf16x8 a = *reinterpret_cast<const bf16x8*>(ldsA + ((size_t)kb*64 + l)*16);
        acc[kb&3] = __builtin_amdgcn_mfma_f32_16x16x32_bf16(a, wfrag[16+kb], acc[kb&3], 0,0,0);
      }
      f32x4 r = (acc[0]+acc[1])+(acc[2]+acc[3]);
      float pr[4];
#pragma unroll
      for (int rr=0;rr<4;rr++){
        float p = r[rr] + bias1;
        pr[rr] = p;
        float a = isU1 ? tanhf(p) : sigmoidf_(p);
        acts[wave][(kq<<2)+rr][col] = (__bf16)a;   // wave-local transpose scratch
      }
      // wide act stores: 32 lanes x 16B (2x8B), 128B-contiguous runs.
      // DS is in-order per wave -> reads see this wave's writes, no barrier.
      if (l < 32){
        int row = l & 15, half = l >> 4;
        const u64* srcg = reinterpret_cast<const u64*>(&acts[wave][row][half*8]);
        u64 v0 = srcg[0], v1 = srcg[1];
        st_cc64(actw, v0); st_cc64(actw+1, v1);
      }
      if (isQb && wave==0){
        if (col < 4){
#pragma unroll
          for (int rr=0;rr<4;rr++) pre4[(kq<<2)+rr][col] = pr[rr];
        }
        if (l < 16){
          float th = pre4[l][0]*pq0 + pre4[l][1]*pq1 + pre4[l][2]*pq2 + pre4[l][3]*pq3;
          float z = cosf(2.f*th);
          st_cc32(&zact[gq*B_SZ + mt1*16 + l], (gq==2) ? z : sigmoidf_(z));
        }
      }
    }

    bar_arrive(flags, (unsigned)(2*s+1));
    bar_wait(flags, (unsigned)(2*s+1));

    // ================= phase 2: comb + cell update =================
    float hn, cn; size_t oidx;
    {
      // zact loads first (ready well before the gate math)
      float zf = ld_cc32f(&zact[      b2]);
      float zi = ld_cc32f(&zact[ 64 + b2]);
      float zu = ld_cc32f(&zact[128 + b2]);
      float zo = ld_cc32f(&zact[192 + b2]);

      // act fragments DIRECT to registers: own gate tile, 4 chunks of 8 kb,
      // double-buffered (issue chunk c+1 before consuming chunk c)
      const u64* ap = (const u64*)actF + (size_t)(wave*8 + mt2)*2048 + (size_t)slot2*2;
      const bf16x8* bf0 = (const bf16x8*)ldsWc + l;
      const bf16x8* bf1 = bf0 + 2048;
      f32x4 acc2[4] = {{0,0,0,0},{0,0,0,0},{0,0,0,0},{0,0,0,0}};
      u64 A0lo[8], A0hi[8], A1lo[8], A1hi[8];
#pragma unroll
      for (int i=0;i<8;i++){
        A0lo[i] = ld_cc64(ap + (size_t)i*64);
        A0hi[i] = ld_cc64(ap + (size_t)i*64 + 1);
      }
#pragma unroll
      for (int c=0;c<4;c++){
        u64* clo = (c&1) ? A1lo : A0lo;
        u64* chi = (c&1) ? A1hi : A0hi;
        u64* nlo = (c&1) ? A0lo : A1lo;
        u64* nhi = (c&1) ? A0hi : A1hi;
        if (c < 3){
#pragma unroll
          for (int i=0;i<8;i++){
            nlo[i] = ld_cc64(ap + (size_t)((c+1)*8 + i)*64);
            nhi[i] = ld_cc64(ap + (size_t)((c+1)*8 + i)*64 + 1);
          }
        }
#pragma unroll
        for (int i=0;i<8;i++){
          int kb = c*8 + i;
          union{u64 u[2]; bf16x8 v;} a; a.u[0]=clo[i]; a.u[1]=chi[i];
          acc2[kb&1]     = __builtin_amdgcn_mfma_f32_16x16x32_bf16(a.v, bf0[(size_t)kb*64], acc2[kb&1], 0,0,0);
          acc2[2+(kb&1)] = __builtin_amdgcn_mfma_f32_16x16x32_bf16(a.v, bf1[(size_t)kb*64], acc2[2+(kb&1)], 0,0,0);
        }
      }
      f32x4 rA = acc2[0]+acc2[1];
      f32x4 rB = acc2[2]+acc2[3];
#pragma unroll
      for (int rr=0;rr<4;rr++){
        int row = (kq<<2) + rr;            // rows 8..15 duplicates, discard
        if (row < 8){
          gx[wave][row][col]      = rA[rr];
          gx[wave][row][16 + col] = rB[rr];
        }
      }
      __syncthreads();

      float fg = sigmoidf_(gx[0][r2][c2] + bc2 + zf*wl2);
      float ig = sigmoidf_(gx[1][r2][c2] + bc2 + zi*wl2);
      float gg = tanhf(    gx[2][r2][c2] + bc2 + zu*wl2);
      float og = sigmoidf_(gx[3][r2][c2] + bc2 + zo*wl2);
      cn = fg*creg + ig*gg;
      creg = cn;
      hn = og*tanhf(cn);
      // wide hx stores: wave-local LDS transpose -> 8 lanes x 16B per wave
      hxs[r2][c2] = (__bf16)hn;
      if (l < 8){
        const u64* srcg = reinterpret_cast<const u64*>(&hxs[2*wave + (l>>2)][(l&3)*8]);
        u64 v0 = srcg[0], v1 = srcg[1];
        st_cc64(hxw, v0); st_cc64(hxw+1, v1);
      }
      oidx = (size_t)b2*H_SZ + h2;
    }

    bar_arrive(flags, (unsigned)(2*s+2));

    // out stores AFTER arrive: never read in-kernel; drain under next poll
    __builtin_nontemporal_store(hn, &out[(size_t)s*B_SZ*H_SZ + oidx]);
    if (s == S_LEN-1){
      __builtin_nontemporal_store(hn, &out[SBH + oidx]);
      __builtin_nontemporal_store(cn, &out[SBH + (size_t)B_SZ*H_SZ + oidx]);
    }
  }
}

// ---------------- launch ----------------

extern "C" void kernel_launch(void* const* d_in, const int* in_sizes, int n_in,
                              void* d_out, int out_size, void* d_ws, size_t ws_size,
                              hipStream_t stream){
  const float* inputs = (const float*)d_in[0];
  const float* Wf  = (const float*)d_in[1];
  const float* bf_ = (const float*)d_in[2];
  const float* Wi  = (const float*)d_in[3];
  const float* bi_ = (const float*)d_in[4];
  const float* Wu  = (const float*)d_in[5];
  const float* bu_ = (const float*)d_in[6];
  const float* Wo  = (const float*)d_in[7];
  const float* bo_ = (const float*)d_in[8];
  const float* pf  = (const float*)d_in[9];
  const float* piq = (const float*)d_in[10];
  const float* pu  = (const float*)d_in[11];
  const float* po  = (const float*)d_in[12];
  const float* Wc  = (const float*)d_in[13];
  const float* bc  = (const float*)d_in[14];
  float* out = (float*)d_out;

  __bf16* W4p = (__bf16*)d_ws;                        // 6,291,456 bf16
  __bf16* Wcp = W4p + (size_t)256*48*64*8;            // 1,048,576 bf16
  __bf16* xF  = Wcp + (size_t)64*32*64*8;             // 8,388,608 bf16
  __bf16* actF = xF + (size_t)S_LEN*B_SZ*I_SZ;        // 262,144 bf16
  __bf16* hxF = actF + (size_t)4*B_SZ*H_SZ;           // 65,536 bf16
  float*  zact = (float*)(hxF + (size_t)B_SZ*H_SZ);   // 256 f32
  unsigned* flags = (unsigned*)(zact + 256);          // 256 u32

  pack_w4_k<<<256*48, 64, 0, stream>>>(Wf, Wi, Wu, Wo, W4p);
  pack_wc_k<<<64*32, 64, 0, stream>>>(Wc, Wcp);
  pack_x_k<<<S_LEN*4, 256, 0, stream>>>(inputs, xF);
  init_h_k<<<256, 256, 0, stream>>>(hxF);
  hipMemsetAsync(flags, 0, NBLK*sizeof(unsigned), stream);

  qlstm_persist_k<<<NBLK, 256, 0, stream>>>(
      xF, hxF, W4p, Wcp, bf_, bi_, bu_, bo_, pf, piq, pu, po,
      Wc + (size_t)H_SZ*H_SZ, bc, actF, zact, out, flags);
}